// Round 23
// baseline (81.819 us; speedup 1.0000x reference)
//
#include <hip/hip_runtime.h>

#define NP 64
#define HID 1024
#define DIN 16
#define BATCH 2048
#define DTOT 18433
#define OFF_B1 16384
#define OFF_W2 17408
#define OFF_B2 18432
#define STEPC 0.0015625f  /* 0.1/64 */
#define GCH 128
#define NGBLK 145   /* ceil(18433/128) */

typedef __attribute__((ext_vector_type(8))) short bf16x8;
typedef __attribute__((ext_vector_type(4))) short short4v;
typedef __attribute__((ext_vector_type(4))) float f32x4;

__device__ __forceinline__ short f2bf(float f) {
  union { float f; unsigned u; } v; v.f = f;
  unsigned r = v.u + 0x7FFFu + ((v.u >> 16) & 1u);
  return (short)(r >> 16);
}

// convert 8 consecutive fp32 to a bf16x8 fragment
__device__ __forceinline__ bf16x8 cvt8(const float* __restrict__ p) {
  f32x4 q0 = *(const f32x4*)p;
  f32x4 q1 = *(const f32x4*)(p + 4);
  bf16x8 o;
  o[0] = f2bf(q0[0]); o[1] = f2bf(q0[1]); o[2] = f2bf(q0[2]); o[3] = f2bf(q0[3]);
  o[4] = f2bf(q1[0]); o[5] = f2bf(q1[1]); o[6] = f2bf(q1[2]); o[7] = f2bf(q1[3]);
  return o;
}

__device__ __forceinline__ float theta_at(int i, int d,
    const float* __restrict__ W1, const float* __restrict__ b1,
    const float* __restrict__ W2, const float* __restrict__ b2) {
  if (d < OFF_B1) return W1[i * 16384 + d];
  if (d < OFF_W2) return b1[i * HID + (d - OFF_B1)];
  if (d < OFF_B2) return W2[i * HID + (d - OFF_W2)];
  return b2[i];
}

// K0: one-time bf16 conversions of X only (W1 converted inline by consumers).
// grid(16) x 256.
__global__ __launch_bounds__(256) void k_prep(
    const float* __restrict__ X, short* __restrict__ Xb,
    short* __restrict__ XtS) {
  const int gid = blockIdx.x * 256 + threadIdx.x;  // 4096 threads
  {
    const size_t base = (size_t)gid * 8;
    *(bf16x8*)&Xb[base] = cvt8(&X[base]);
  }
  if (gid < 2048) {
    const int d = gid & 15;
    const int b0 = (gid >> 4) * 16;
    #pragma unroll
    for (int q = 0; q < 4; ++q) {
      short4v s4;
      #pragma unroll
      for (int t = 0; t < 4; ++t) s4[t] = f2bf(X[(b0 + q * 4 + t) * DIN + d]);
      *(short4v*)&XtS[d * 2048 + b0 + q * 4] = s4;
    }
  }
}

// MEGA1: blocks [0,512) = forward (n=bx>>3, bg=bx&7); [512,657) = gram partial.
// W1 fragments converted inline (once per block, amortized over 128 MFMAs).
__global__ __launch_bounds__(512) void k_fwd_gram(
    const float* __restrict__ b1, const float* __restrict__ W2,
    const float* __restrict__ b2, const short* __restrict__ Xb,
    const float* __restrict__ y, short* __restrict__ ebf_ws,
    float* __restrict__ Pb2, const float* __restrict__ W1,
    float* __restrict__ gpart) {
  __shared__ __align__(16) char smem[34816];
  const int bx = blockIdx.x;
  const int tid = threadIdx.x;

  if (bx < 512) {
    // ---------------- forward ----------------
    const int n = bx >> 3, bg = bx & 7;
    const int w = tid >> 6, l = tid & 63;
    const int lrow = l & 15, lhi = l >> 4;
    float (*yhp)[256] = (float (*)[256])smem;
    float* pbl = (float*)(smem + 8192);

    const bf16x8 zf = {0, 0, 0, 0, 0, 0, 0, 0};
    bf16x8 af[8];
    f32x4 b1v[8], w2v[8];
    #pragma unroll
    for (int ktl = 0; ktl < 8; ++ktl) {
      const int krow = n * HID + (w * 8 + ktl) * 16;
      af[ktl] = (lhi < 2) ? cvt8(&W1[(size_t)(krow + lrow) * DIN + lhi * 8]) : zf;
      b1v[ktl] = *(const f32x4*)&b1[krow + lhi * 4];
      w2v[ktl] = *(const f32x4*)&W2[krow + lhi * 4];
    }

    for (int bt = 0; bt < 16; ++bt) {
      const int bbase = bg * 256 + bt * 16;
      const bf16x8 bf = (lhi < 2) ? *(const bf16x8*)&Xb[(size_t)(bbase + lrow) * DIN + lhi * 8] : zf;
      float ya = 0.f;
      __builtin_amdgcn_s_setprio(2);
      #pragma unroll
      for (int ktl = 0; ktl < 8; ++ktl) {
        f32x4 c = {0.f, 0.f, 0.f, 0.f};
        c = __builtin_amdgcn_mfma_f32_16x16x32_bf16(af[ktl], bf, c, 0, 0, 0);
        #pragma unroll
        for (int r = 0; r < 4; ++r) {
          const float pre = c[r] + b1v[ktl][r];
          ya = fmaf(fmaxf(pre, 0.f), w2v[ktl][r], ya);
        }
      }
      __builtin_amdgcn_s_setprio(0);
      ya += __shfl_xor(ya, 16);
      ya += __shfl_xor(ya, 32);
      if (l < 16) yhp[w][bt * 16 + lrow] = ya;
    }
    __syncthreads();
    float ev = 0.f;
    if (tid < 256) {
      float sum = 0.f;
      #pragma unroll
      for (int q = 0; q < 8; ++q) sum += yhp[q][tid];
      const int b = bg * 256 + tid;
      ev = y[b] - (sum + b2[n]);
      ebf_ws[n * BATCH + b] = f2bf(ev);
    }
    #pragma unroll
    for (int off = 1; off < 64; off <<= 1) ev += __shfl_xor(ev, off);
    if (tid < 256 && l == 0) pbl[w] = ev;
    __syncthreads();
    if (tid == 0) Pb2[n * 8 + bg] = pbl[0] + pbl[1] + pbl[2] + pbl[3];
  } else {
    // ---------------- gram partial ----------------
    float (*ths)[68] = (float (*)[68])smem;
    const int gb = bx - 512;
    const int c0 = gb * GCH;
    for (int idx = tid; idx < 2048; idx += 512) {
      const int i = idx >> 5;            // 0..63
      const int dd = (idx & 31) * 4;     // 0..124
      const int d = c0 + dd;
      float v0, v1, v2, v3;
      if (d + 3 < DTOT) {
        f32x4 q;
        if (d < OFF_B1)      q = *(const f32x4*)&W1[i * 16384 + d];
        else if (d < OFF_W2) q = *(const f32x4*)&b1[i * HID + (d - OFF_B1)];
        else                 q = *(const f32x4*)&W2[i * HID + (d - OFF_W2)];
        v0 = q[0]; v1 = q[1]; v2 = q[2]; v3 = q[3];
      } else {
        v0 = (d     < DTOT) ? theta_at(i, d,     W1, b1, W2, b2) : 0.f;
        v1 = (d + 1 < DTOT) ? theta_at(i, d + 1, W1, b1, W2, b2) : 0.f;
        v2 = (d + 2 < DTOT) ? theta_at(i, d + 2, W1, b1, W2, b2) : 0.f;
        v3 = (d + 3 < DTOT) ? theta_at(i, d + 3, W1, b1, W2, b2) : 0.f;
      }
      ths[dd][i] = v0; ths[dd + 1][i] = v1; ths[dd + 2][i] = v2; ths[dd + 3][i] = v3;
    }
    __syncthreads();
    if (tid < 256) {
      const int i0 = (tid >> 4) << 2;
      const int j0 = (tid & 15) << 2;
      float acc[4][4] = {};
      for (int dc = 0; dc < 128; ++dc) {
        const f32x4 av = *(const f32x4*)&ths[dc][i0];
        const f32x4 bv = *(const f32x4*)&ths[dc][j0];
        #pragma unroll
        for (int a = 0; a < 4; ++a)
          #pragma unroll
          for (int bj = 0; bj < 4; ++bj)
            acc[a][bj] = fmaf(av[a], bv[bj], acc[a][bj]);
      }
      float* __restrict__ gp = gpart + gb * 4096;
      #pragma unroll
      for (int a = 0; a < 4; ++a)
        #pragma unroll
        for (int bj = 0; bj < 4; ++bj)
          gp[(i0 + a) * 64 + j0 + bj] = acc[a][bj];
    }
  }
}

// MEGA2: blocks [0,1024) = backward partials; [1024,1088) = gram reduce.
// W1 fragment (b1f) converted inline; epilogue computes gw2 dot partial.
__global__ __launch_bounds__(512) void k_bwd_red(
    const float* __restrict__ b1, const float* __restrict__ W1,
    const short* __restrict__ Xb, const short* __restrict__ XtS,
    const short* __restrict__ ebf_ws, float* __restrict__ dwp,
    float* __restrict__ gbp, float* __restrict__ gw2p,
    const float* __restrict__ gpart, float* __restrict__ gram) {
  __shared__ __align__(16) char smem[34816];
  const int bx = blockIdx.x;
  const int tid = threadIdx.x;

  if (bx < 1024) {
    // ---------------- backward ----------------
    const int n = bx >> 4, kg = (bx >> 1) & 7, bs = bx & 1;
    const int w = tid >> 6, l = tid & 63;
    const int lrow = l & 15, lhi = l >> 4;
    short* __restrict__ Xa  = (short*)smem;            // 4096 shorts
    short* __restrict__ Xt  = (short*)(smem + 8192);   // 4096 shorts
    short* __restrict__ Gt  = (short*)(smem + 16384);  // 8192 shorts (2 slots)
    short* __restrict__ els = (short*)(smem + 32768);  // 1024 shorts

    if (tid < 256)
      *(short4v*)&els[tid * 4] = *(const short4v*)&ebf_ws[n * BATCH + bs * 1024 + tid * 4];

    const int kt_g = kg * 8 + w;
    const int kglob = kt_g * 16 + lrow;
    const bf16x8 zf = {0, 0, 0, 0, 0, 0, 0, 0};
    const short one_bf = (short)0x3F80;
    const bf16x8 onesf = {one_bf, one_bf, one_bf, one_bf, one_bf, one_bf, one_bf, one_bf};
    const bf16x8 b1f = (lhi < 2) ? cvt8(&W1[(size_t)(n * HID + kglob) * DIN + lhi * 8]) : zf;
    const float b1r = b1[n * HID + kglob];
    short* __restrict__ GtW = &Gt[w * 1024];  // 2 slots of 512
    const int xw = (lrow & 7) << 3;
    f32x4 c2 = {0.f, 0.f, 0.f, 0.f};
    f32x4 c3 = {0.f, 0.f, 0.f, 0.f};

    auto computeG = [&](int ch, int bt8, short* __restrict__ slot) {
      #pragma unroll
      for (int rt = 0; rt < 2; ++rt) {
        const int bl = bt8 * 32 + rt * 16 + lrow;
        const bf16x8 a1 = (lhi < 2) ? *(const bf16x8*)&Xa[(bl * 16 + lhi * 8) ^ xw] : zf;
        f32x4 c1 = {0.f, 0.f, 0.f, 0.f};
        c1 = __builtin_amdgcn_mfma_f32_16x16x32_bf16(a1, b1f, c1, 0, 0, 0);
        const short4v es = *(const short4v*)&els[ch * 256 + bt8 * 32 + rt * 16 + lhi * 4];
        short4v gg;
        #pragma unroll
        for (int r = 0; r < 4; ++r) {
          const float pre = c1[r] + b1r;
          gg[r] = (pre > 0.f) ? es[r] : (short)0;
        }
        *(short4v*)&slot[(lrow * 32 + rt * 16 + lhi * 4) ^ xw] = gg;
      }
    };

    for (int ch = 0; ch < 4; ++ch) {
      __syncthreads();
      {
        const int b = tid >> 1, half = tid & 1;
        *(bf16x8*)&Xa[(b * 16 + half * 8) ^ ((b & 7) << 3)] =
            *(const bf16x8*)&Xb[(size_t)(bs * 1024 + ch * 256 + b) * DIN + half * 8];
        const int d = tid >> 5, c8 = (tid & 31) * 8;
        *(bf16x8*)&Xt[(d * 256 + c8) ^ ((d & 7) << 3)] =
            *(const bf16x8*)&XtS[d * 2048 + bs * 1024 + ch * 256 + c8];
      }
      __syncthreads();
      computeG(ch, 0, GtW);  // prologue: G(0) -> slot 0
      #pragma unroll
      for (int bt8 = 0; bt8 < 8; ++bt8) {
        short* __restrict__ cur = &GtW[(bt8 & 1) * 512];
        short* __restrict__ nxt = &GtW[((bt8 & 1) ^ 1) * 512];
        const bf16x8 a2f = *(const bf16x8*)&cur[(lrow * 32 + lhi * 8) ^ xw];
        const bf16x8 b2f = *(const bf16x8*)&Xt[(lrow * 256 + bt8 * 32 + lhi * 8) ^ xw];
        if (bt8 < 7) computeG(ch, bt8 + 1, nxt);
        __builtin_amdgcn_s_setprio(2);
        c2 = __builtin_amdgcn_mfma_f32_16x16x32_bf16(a2f, b2f, c2, 0, 0, 0);
        c3 = __builtin_amdgcn_mfma_f32_16x16x32_bf16(a2f, onesf, c3, 0, 0, 0);
        __builtin_amdgcn_s_setprio(0);
      }
    }

    // dW1raw partials + gw2 dot partials (pr = c2 . W1row over lrow lanes)
    float* __restrict__ dw = dwp + (size_t)(bs * NP + n) * HID * 16;
    float pr[4];
    #pragma unroll
    for (int r = 0; r < 4; ++r) {
      const int k = kt_g * 16 + lhi * 4 + r;
      const float w1val = W1[(n * HID + k) * DIN + lrow];
      dw[k * 16 + lrow] = c2[r];
      pr[r] = c2[r] * w1val;
    }
    #pragma unroll
    for (int off = 1; off < 16; off <<= 1) {
      #pragma unroll
      for (int r = 0; r < 4; ++r) pr[r] += __shfl_xor(pr[r], off);
    }
    // redistribute: reader lane l<16 needs (r=l&3, lhi=l>>2)
    const int l3 = l & 3;
    const float pv = (l3 == 0) ? pr[0] : (l3 == 1) ? pr[1] : (l3 == 2) ? pr[2] : pr[3];
    const float gv = (l3 == 0) ? c3[0] : (l3 == 1) ? c3[1] : (l3 == 2) ? c3[2] : c3[3];
    const int src = (((l & 15) >> 2) << 4) | (l & 15);
    const float gw2dot = __shfl(pv, src);
    const float gb1v = __shfl(gv, src);
    if (l < 16) {
      gbp[(size_t)(bs * NP + n) * HID + kt_g * 16 + l] = gb1v;
      gw2p[(size_t)(bs * NP + n) * HID + kt_g * 16 + l] = gw2dot;
    }
  } else {
    // ---------------- gram reduce ----------------
    float (*red)[64] = (float (*)[64])smem;
    const int gb = bx - 1024;
    const int pl = tid & 63;
    const int sl = tid >> 6;   // 0..7
    const int pair = gb * 64 + pl;
    float a = 0.f;
    for (int p = sl; p < NGBLK; p += 8) a += gpart[p * 4096 + pair];
    red[sl][pl] = a;
    __syncthreads();
    if (tid < 64) {
      float t = 0.f;
      #pragma unroll
      for (int q = 0; q < 8; ++q) t += red[q][tid];
      gram[gb * 64 + tid] = t;
    }
  }
}

// K5 (k_fin folded): out = theta*(1+c*s) + c*(kd@V); V computed from partials
// during staging — all regions uniform 2-3 loads/element. grid(145) x 256.
__global__ __launch_bounds__(256) void k_update(
    const float* __restrict__ W1, const float* __restrict__ b1,
    const float* __restrict__ W2, const float* __restrict__ b2,
    const float* __restrict__ gram, const float* __restrict__ dwp,
    const float* __restrict__ gbp, const float* __restrict__ gw2p,
    const float* __restrict__ Pb2, float* __restrict__ vout) {
  __shared__ float Vs[64][132];
  __shared__ float kds[4096];
  __shared__ float ss[64];
  __shared__ float sq[64];
  const int c0 = blockIdx.x * GCH;
  const int tid = threadIdx.x;

  // ---- V staging from partials ----
  if (c0 + GCH <= OFF_B1) {
    // W1 region: V = (s0+s1)*w2[k] - 2*W1
    for (int idx = tid; idx < 2048; idx += 256) {
      const int i = idx >> 5, dd = (idx & 31) * 4;
      const size_t o = (size_t)i * 16384 + c0 + dd;
      const f32x4 s0 = *(const f32x4*)&dwp[o];
      const f32x4 s1 = *(const f32x4*)&dwp[o + (size_t)NP * 16384];
      const f32x4 ww = *(const f32x4*)&W1[o];
      const float w2r = W2[i * HID + ((c0 + dd) >> 4)];
      #pragma unroll
      for (int c = 0; c < 4; ++c)
        Vs[i][dd + c] = (s0[c] + s1[c]) * w2r - 2.f * ww[c];
    }
  } else if (c0 + GCH <= OFF_W2) {
    // b1 region: V = gb1*w2 - 2*b1
    for (int idx = tid; idx < 2048; idx += 256) {
      const int i = idx >> 5, dd = (idx & 31) * 4;
      const size_t o = (size_t)i * HID + (c0 + dd - OFF_B1);
      const f32x4 g0 = *(const f32x4*)&gbp[o];
      const f32x4 g1 = *(const f32x4*)&gbp[o + (size_t)NP * HID];
      const f32x4 w2v = *(const f32x4*)&W2[o];
      const f32x4 b1v = *(const f32x4*)&b1[o];
      #pragma unroll
      for (int c = 0; c < 4; ++c)
        Vs[i][dd + c] = (g0[c] + g1[c]) * w2v[c] - 2.f * b1v[c];
    }
  } else if (c0 + GCH <= OFF_B2) {
    // W2 region: V = (d0+d1) + b1*gb1 - 2*w2  (dot precomputed in k_bwd)
    for (int idx = tid; idx < 2048; idx += 256) {
      const int i = idx >> 5, dd = (idx & 31) * 4;
      const size_t o = (size_t)i * HID + (c0 + dd - OFF_W2);
      const f32x4 d0 = *(const f32x4*)&gw2p[o];
      const f32x4 d1 = *(const f32x4*)&gw2p[o + (size_t)NP * HID];
      const f32x4 g0 = *(const f32x4*)&gbp[o];
      const f32x4 g1 = *(const f32x4*)&gbp[o + (size_t)NP * HID];
      const f32x4 b1v = *(const f32x4*)&b1[o];
      const f32x4 w2v = *(const f32x4*)&W2[o];
      #pragma unroll
      for (int c = 0; c < 4; ++c)
        Vs[i][dd + c] = (d0[c] + d1[c]) + b1v[c] * (g0[c] + g1[c]) - 2.f * w2v[c];
    }
  } else {
    // b2 block (c0 == 18432): only column 0 valid
    for (int idx = tid; idx < 2048; idx += 256) {
      const int i = idx >> 5, dd = (idx & 31) * 4;
      f32x4 v = {0.f, 0.f, 0.f, 0.f};
      if (dd == 0) {
        float sb = 0.f;
        #pragma unroll
        for (int q = 0; q < 8; ++q) sb += Pb2[i * 8 + q];
        v[0] = sb - 2.f * b2[i];
      }
      *(f32x4*)&Vs[i][dd] = v;
    }
  }

  if (tid < 64) sq[tid] = gram[tid * 65];
  __syncthreads();
  for (int q = tid; q < 4096; q += 256) {
    const int i = q >> 6, j = q & 63;
    const float d2 = fmaxf(sq[i] + sq[j] - 2.f * gram[q], 0.f);
    kds[q] = expf(-0.5f * d2);
  }
  __syncthreads();
  if (tid < 64) {
    float a = 0.f;
    for (int j = 0; j < 64; ++j) a += kds[tid * 64 + j];
    ss[tid] = a;
  }
  __syncthreads();
  const int col4 = (tid & 31) * 4;
  const int i0 = (tid >> 5) * 8;
  f32x4 acc[8] = {};
  for (int j = 0; j < 64; ++j) {
    const f32x4 vv = *(const f32x4*)&Vs[j][col4];
    const f32x4 k0 = *(const f32x4*)&kds[j * 64 + i0];
    const f32x4 k1 = *(const f32x4*)&kds[j * 64 + i0 + 4];
    #pragma unroll
    for (int a = 0; a < 4; ++a) {
      acc[a][0] = fmaf(k0[a], vv[0], acc[a][0]);
      acc[a][1] = fmaf(k0[a], vv[1], acc[a][1]);
      acc[a][2] = fmaf(k0[a], vv[2], acc[a][2]);
      acc[a][3] = fmaf(k0[a], vv[3], acc[a][3]);
    }
    #pragma unroll
    for (int a = 0; a < 4; ++a) {
      acc[a + 4][0] = fmaf(k1[a], vv[0], acc[a + 4][0]);
      acc[a + 4][1] = fmaf(k1[a], vv[1], acc[a + 4][1]);
      acc[a + 4][2] = fmaf(k1[a], vv[2], acc[a + 4][2]);
      acc[a + 4][3] = fmaf(k1[a], vv[3], acc[a + 4][3]);
    }
  }
  #pragma unroll
  for (int a = 0; a < 8; ++a) {
    const int i = i0 + a;
    const float f = 1.f + STEPC * ss[i];
    #pragma unroll
    for (int cc = 0; cc < 4; ++cc) {
      const int d = c0 + col4 + cc;
      if (d < DTOT) {
        const float th = theta_at(i, d, W1, b1, W2, b2);
        vout[(size_t)i * DTOT + d] = th * f + STEPC * acc[a][cc];
      }
    }
  }
}

extern "C" void kernel_launch(void* const* d_in, const int* in_sizes, int n_in,
                              void* d_out, int out_size, void* d_ws, size_t ws_size,
                              hipStream_t stream) {
  const float* W1 = (const float*)d_in[0];
  const float* b1 = (const float*)d_in[1];
  const float* W2 = (const float*)d_in[2];
  const float* b2 = (const float*)d_in[3];
  const float* X  = (const float*)d_in[4];
  const float* y  = (const float*)d_in[5];
  float* vout = (float*)d_out;

  float* Pb2   = (float*)d_ws;              // 512 f
  float* gpart = Pb2 + 512;                 // 593920 f
  float* gram  = gpart + NGBLK * 4096;      // 4096 f
  float* dwp   = gram + 4096;               // 2*64*1024*16 = 2097152 f
  float* gbp   = dwp + 2 * NP * HID * 16;   // 131072 f
  float* gw2p  = gbp + 2 * NP * HID;        // 131072 f
  short* Xb    = (short*)(gw2p + 2 * NP * HID);  // 32768 s
  short* XtS   = Xb + BATCH * DIN;          // 32768 s
  short* ebf   = XtS + BATCH * DIN;         // 131072 s

  k_prep<<<16, 256, 0, stream>>>(X, Xb, XtS);
  k_fwd_gram<<<512 + NGBLK, 512, 0, stream>>>(b1, W2, b2, Xb, y, ebf, Pb2, W1, gpart);
  k_bwd_red<<<1024 + 64, 512, 0, stream>>>(b1, W1, Xb, XtS, ebf, dwp, gbp, gw2p, gpart, gram);
  k_update<<<NGBLK, 256, 0, stream>>>(W1, b1, W2, b2, gram, dwp, gbp, gw2p, Pb2, vout);
}

// Round 24
// 78.964 us; speedup vs baseline: 1.0362x; 1.0362x over previous
//
#include <hip/hip_runtime.h>

#define NP 64
#define HID 1024
#define DIN 16
#define BATCH 2048
#define DTOT 18433
#define OFF_B1 16384
#define OFF_W2 17408
#define OFF_B2 18432
#define STEPC 0.0015625f  /* 0.1/64 */
#define GCH 128
#define NGBLK 145   /* ceil(18433/128) */

typedef __attribute__((ext_vector_type(8))) short bf16x8;
typedef __attribute__((ext_vector_type(4))) short short4v;
typedef __attribute__((ext_vector_type(4))) float f32x4;

__device__ __forceinline__ short f2bf(float f) {
  union { float f; unsigned u; } v; v.f = f;
  unsigned r = v.u + 0x7FFFu + ((v.u >> 16) & 1u);
  return (short)(r >> 16);
}

__device__ __forceinline__ float theta_at(int i, int d,
    const float* __restrict__ W1, const float* __restrict__ b1,
    const float* __restrict__ W2, const float* __restrict__ b2) {
  if (d < OFF_B1) return W1[i * 16384 + d];
  if (d < OFF_W2) return b1[i * HID + (d - OFF_B1)];
  if (d < OFF_B2) return W2[i * HID + (d - OFF_W2)];
  return b2[i];
}

// K0: one-time bf16 conversions. grid(512) x 256.
__global__ __launch_bounds__(256) void k_prep(
    const float* __restrict__ W1, const float* __restrict__ X,
    short* __restrict__ W1b, short* __restrict__ Xb, short* __restrict__ XtS) {
  const int gid = blockIdx.x * 256 + threadIdx.x;  // 131072 threads
  {
    const size_t base = (size_t)gid * 8;
    f32x4 a = *(const f32x4*)&W1[base];
    f32x4 b = *(const f32x4*)&W1[base + 4];
    bf16x8 o;
    o[0] = f2bf(a[0]); o[1] = f2bf(a[1]); o[2] = f2bf(a[2]); o[3] = f2bf(a[3]);
    o[4] = f2bf(b[0]); o[5] = f2bf(b[1]); o[6] = f2bf(b[2]); o[7] = f2bf(b[3]);
    *(bf16x8*)&W1b[base] = o;
  }
  if (gid < 4096) {
    const size_t base = (size_t)gid * 8;
    f32x4 a = *(const f32x4*)&X[base];
    f32x4 b = *(const f32x4*)&X[base + 4];
    bf16x8 o;
    o[0] = f2bf(a[0]); o[1] = f2bf(a[1]); o[2] = f2bf(a[2]); o[3] = f2bf(a[3]);
    o[4] = f2bf(b[0]); o[5] = f2bf(b[1]); o[6] = f2bf(b[2]); o[7] = f2bf(b[3]);
    *(bf16x8*)&Xb[base] = o;
  }
  if (gid < 2048) {
    const int d = gid & 15;
    const int b0 = (gid >> 4) * 16;
    #pragma unroll
    for (int q = 0; q < 4; ++q) {
      short4v s4;
      #pragma unroll
      for (int t = 0; t < 4; ++t) s4[t] = f2bf(X[(b0 + q * 4 + t) * DIN + d]);
      *(short4v*)&XtS[d * 2048 + b0 + q * 4] = s4;
    }
  }
}

// MEGA1: blocks [0,512) = forward (n=bx>>3, bg=bx&7); [512,657) = gram partial.
// MFMA clusters wrapped in s_setprio (T5: waves drift out of phase in the
// barrier-free bt loop, so the CU scheduler can favor MFMA-issuing waves).
__global__ __launch_bounds__(512) void k_fwd_gram(
    const short* __restrict__ W1b, const float* __restrict__ b1,
    const float* __restrict__ W2, const float* __restrict__ b2,
    const short* __restrict__ Xb, const float* __restrict__ y,
    short* __restrict__ ebf_ws, float* __restrict__ Pb2,
    const float* __restrict__ W1, float* __restrict__ gpart) {
  __shared__ __align__(16) char smem[34816];
  const int bx = blockIdx.x;
  const int tid = threadIdx.x;

  if (bx < 512) {
    // ---------------- forward ----------------
    const int n = bx >> 3, bg = bx & 7;
    const int w = tid >> 6, l = tid & 63;
    const int lrow = l & 15, lhi = l >> 4;
    float (*yhp)[256] = (float (*)[256])smem;
    float* pbl = (float*)(smem + 8192);

    const bf16x8 zf = {0, 0, 0, 0, 0, 0, 0, 0};
    bf16x8 af[8];
    f32x4 b1v[8], w2v[8];
    #pragma unroll
    for (int ktl = 0; ktl < 8; ++ktl) {
      const int krow = n * HID + (w * 8 + ktl) * 16;
      af[ktl] = (lhi < 2) ? *(const bf16x8*)&W1b[(size_t)(krow + lrow) * DIN + lhi * 8] : zf;
      b1v[ktl] = *(const f32x4*)&b1[krow + lhi * 4];
      w2v[ktl] = *(const f32x4*)&W2[krow + lhi * 4];
    }

    for (int bt = 0; bt < 16; ++bt) {
      const int bbase = bg * 256 + bt * 16;
      const bf16x8 bf = (lhi < 2) ? *(const bf16x8*)&Xb[(size_t)(bbase + lrow) * DIN + lhi * 8] : zf;
      float ya = 0.f;
      __builtin_amdgcn_s_setprio(2);
      #pragma unroll
      for (int ktl = 0; ktl < 8; ++ktl) {
        f32x4 c = {0.f, 0.f, 0.f, 0.f};
        c = __builtin_amdgcn_mfma_f32_16x16x32_bf16(af[ktl], bf, c, 0, 0, 0);
        #pragma unroll
        for (int r = 0; r < 4; ++r) {
          const float pre = c[r] + b1v[ktl][r];
          ya = fmaf(fmaxf(pre, 0.f), w2v[ktl][r], ya);
        }
      }
      __builtin_amdgcn_s_setprio(0);
      ya += __shfl_xor(ya, 16);
      ya += __shfl_xor(ya, 32);
      if (l < 16) yhp[w][bt * 16 + lrow] = ya;
    }
    __syncthreads();
    float ev = 0.f;
    if (tid < 256) {
      float sum = 0.f;
      #pragma unroll
      for (int q = 0; q < 8; ++q) sum += yhp[q][tid];
      const int b = bg * 256 + tid;
      ev = y[b] - (sum + b2[n]);
      ebf_ws[n * BATCH + b] = f2bf(ev);
    }
    #pragma unroll
    for (int off = 1; off < 64; off <<= 1) ev += __shfl_xor(ev, off);
    if (tid < 256 && l == 0) pbl[w] = ev;
    __syncthreads();
    if (tid == 0) Pb2[n * 8 + bg] = pbl[0] + pbl[1] + pbl[2] + pbl[3];
  } else {
    // ---------------- gram partial ----------------
    float (*ths)[68] = (float (*)[68])smem;
    const int gb = bx - 512;
    const int c0 = gb * GCH;
    for (int idx = tid; idx < 2048; idx += 512) {
      const int i = idx >> 5;            // 0..63
      const int dd = (idx & 31) * 4;     // 0..124
      const int d = c0 + dd;
      float v0, v1, v2, v3;
      if (d + 3 < DTOT) {
        f32x4 q;
        if (d < OFF_B1)      q = *(const f32x4*)&W1[i * 16384 + d];
        else if (d < OFF_W2) q = *(const f32x4*)&b1[i * HID + (d - OFF_B1)];
        else                 q = *(const f32x4*)&W2[i * HID + (d - OFF_W2)];
        v0 = q[0]; v1 = q[1]; v2 = q[2]; v3 = q[3];
      } else {
        v0 = (d     < DTOT) ? theta_at(i, d,     W1, b1, W2, b2) : 0.f;
        v1 = (d + 1 < DTOT) ? theta_at(i, d + 1, W1, b1, W2, b2) : 0.f;
        v2 = (d + 2 < DTOT) ? theta_at(i, d + 2, W1, b1, W2, b2) : 0.f;
        v3 = (d + 3 < DTOT) ? theta_at(i, d + 3, W1, b1, W2, b2) : 0.f;
      }
      ths[dd][i] = v0; ths[dd + 1][i] = v1; ths[dd + 2][i] = v2; ths[dd + 3][i] = v3;
    }
    __syncthreads();
    if (tid < 256) {
      const int i0 = (tid >> 4) << 2;
      const int j0 = (tid & 15) << 2;
      float acc[4][4] = {};
      for (int dc = 0; dc < 128; ++dc) {
        const f32x4 av = *(const f32x4*)&ths[dc][i0];
        const f32x4 bv = *(const f32x4*)&ths[dc][j0];
        #pragma unroll
        for (int a = 0; a < 4; ++a)
          #pragma unroll
          for (int bj = 0; bj < 4; ++bj)
            acc[a][bj] = fmaf(av[a], bv[bj], acc[a][bj]);
      }
      float* __restrict__ gp = gpart + gb * 4096;
      #pragma unroll
      for (int a = 0; a < 4; ++a)
        #pragma unroll
        for (int bj = 0; bj < 4; ++bj)
          gp[(i0 + a) * 64 + j0 + bj] = acc[a][bj];
    }
  }
}

// MEGA2: blocks [0,1024) = backward partials; [1024,1088) = gram reduce.
// Backward epilogue also computes per-bs gw2 dot partial (c2 . W1row).
__global__ __launch_bounds__(512) void k_bwd_red(
    const float* __restrict__ b1, const float* __restrict__ W1,
    const short* __restrict__ W1b, const short* __restrict__ Xb,
    const short* __restrict__ XtS, const short* __restrict__ ebf_ws,
    float* __restrict__ dwp, float* __restrict__ gbp,
    float* __restrict__ gw2p, const float* __restrict__ gpart,
    float* __restrict__ gram) {
  __shared__ __align__(16) char smem[34816];
  const int bx = blockIdx.x;
  const int tid = threadIdx.x;

  if (bx < 1024) {
    // ---------------- backward ----------------
    const int n = bx >> 4, kg = (bx >> 1) & 7, bs = bx & 1;
    const int w = tid >> 6, l = tid & 63;
    const int lrow = l & 15, lhi = l >> 4;
    short* __restrict__ Xa  = (short*)smem;            // 4096 shorts
    short* __restrict__ Xt  = (short*)(smem + 8192);   // 4096 shorts
    short* __restrict__ Gt  = (short*)(smem + 16384);  // 8192 shorts (2 slots)
    short* __restrict__ els = (short*)(smem + 32768);  // 1024 shorts

    if (tid < 256)
      *(short4v*)&els[tid * 4] = *(const short4v*)&ebf_ws[n * BATCH + bs * 1024 + tid * 4];

    const int kt_g = kg * 8 + w;
    const int kglob = kt_g * 16 + lrow;
    const bf16x8 zf = {0, 0, 0, 0, 0, 0, 0, 0};
    const short one_bf = (short)0x3F80;
    const bf16x8 onesf = {one_bf, one_bf, one_bf, one_bf, one_bf, one_bf, one_bf, one_bf};
    const bf16x8 b1f = (lhi < 2) ? *(const bf16x8*)&W1b[(size_t)(n * HID + kglob) * DIN + lhi * 8] : zf;
    const float b1r = b1[n * HID + kglob];
    short* __restrict__ GtW = &Gt[w * 1024];  // 2 slots of 512
    const int xw = (lrow & 7) << 3;
    f32x4 c2 = {0.f, 0.f, 0.f, 0.f};
    f32x4 c3 = {0.f, 0.f, 0.f, 0.f};

    auto computeG = [&](int ch, int bt8, short* __restrict__ slot) {
      #pragma unroll
      for (int rt = 0; rt < 2; ++rt) {
        const int bl = bt8 * 32 + rt * 16 + lrow;
        const bf16x8 a1 = (lhi < 2) ? *(const bf16x8*)&Xa[(bl * 16 + lhi * 8) ^ xw] : zf;
        f32x4 c1 = {0.f, 0.f, 0.f, 0.f};
        c1 = __builtin_amdgcn_mfma_f32_16x16x32_bf16(a1, b1f, c1, 0, 0, 0);
        const short4v es = *(const short4v*)&els[ch * 256 + bt8 * 32 + rt * 16 + lhi * 4];
        short4v gg;
        #pragma unroll
        for (int r = 0; r < 4; ++r) {
          const float pre = c1[r] + b1r;
          gg[r] = (pre > 0.f) ? es[r] : (short)0;
        }
        *(short4v*)&slot[(lrow * 32 + rt * 16 + lhi * 4) ^ xw] = gg;
      }
    };

    for (int ch = 0; ch < 4; ++ch) {
      __syncthreads();
      {
        const int b = tid >> 1, half = tid & 1;
        *(bf16x8*)&Xa[(b * 16 + half * 8) ^ ((b & 7) << 3)] =
            *(const bf16x8*)&Xb[(size_t)(bs * 1024 + ch * 256 + b) * DIN + half * 8];
        const int d = tid >> 5, c8 = (tid & 31) * 8;
        *(bf16x8*)&Xt[(d * 256 + c8) ^ ((d & 7) << 3)] =
            *(const bf16x8*)&XtS[d * 2048 + bs * 1024 + ch * 256 + c8];
      }
      __syncthreads();
      computeG(ch, 0, GtW);  // prologue: G(0) -> slot 0
      #pragma unroll
      for (int bt8 = 0; bt8 < 8; ++bt8) {
        short* __restrict__ cur = &GtW[(bt8 & 1) * 512];
        short* __restrict__ nxt = &GtW[((bt8 & 1) ^ 1) * 512];
        const bf16x8 a2f = *(const bf16x8*)&cur[(lrow * 32 + lhi * 8) ^ xw];
        const bf16x8 b2f = *(const bf16x8*)&Xt[(lrow * 256 + bt8 * 32 + lhi * 8) ^ xw];
        if (bt8 < 7) computeG(ch, bt8 + 1, nxt);
        __builtin_amdgcn_s_setprio(2);
        c2 = __builtin_amdgcn_mfma_f32_16x16x32_bf16(a2f, b2f, c2, 0, 0, 0);
        c3 = __builtin_amdgcn_mfma_f32_16x16x32_bf16(a2f, onesf, c3, 0, 0, 0);
        __builtin_amdgcn_s_setprio(0);
      }
    }

    // dW1raw partials + gw2 dot partials (pr = c2 . W1row over lrow lanes)
    float* __restrict__ dw = dwp + (size_t)(bs * NP + n) * HID * 16;
    float pr[4];
    #pragma unroll
    for (int r = 0; r < 4; ++r) {
      const int k = kt_g * 16 + lhi * 4 + r;
      const float w1val = W1[(n * HID + k) * DIN + lrow];
      dw[k * 16 + lrow] = c2[r];
      pr[r] = c2[r] * w1val;
    }
    #pragma unroll
    for (int off = 1; off < 16; off <<= 1) {
      #pragma unroll
      for (int r = 0; r < 4; ++r) pr[r] += __shfl_xor(pr[r], off);
    }
    // redistribute: reader lane l<16 needs (r=l&3, lhi=l>>2)
    const int l3 = l & 3;
    const float pv = (l3 == 0) ? pr[0] : (l3 == 1) ? pr[1] : (l3 == 2) ? pr[2] : pr[3];
    const float gv = (l3 == 0) ? c3[0] : (l3 == 1) ? c3[1] : (l3 == 2) ? c3[2] : c3[3];
    const int src = (((l & 15) >> 2) << 4) | (l & 15);
    const float gw2dot = __shfl(pv, src);
    const float gb1v = __shfl(gv, src);
    if (l < 16) {
      gbp[(size_t)(bs * NP + n) * HID + kt_g * 16 + l] = gb1v;
      gw2p[(size_t)(bs * NP + n) * HID + kt_g * 16 + l] = gw2dot;
    }
  } else {
    // ---------------- gram reduce ----------------
    float (*red)[64] = (float (*)[64])smem;
    const int gb = bx - 1024;
    const int pl = tid & 63;
    const int sl = tid >> 6;   // 0..7
    const int pair = gb * 64 + pl;
    float a = 0.f;
    for (int p = sl; p < NGBLK; p += 8) a += gpart[p * 4096 + pair];
    red[sl][pl] = a;
    __syncthreads();
    if (tid < 64) {
      float t = 0.f;
      #pragma unroll
      for (int q = 0; q < 8; ++q) t += red[q][tid];
      gram[gb * 64 + tid] = t;
    }
  }
}

// K5 (k_fin folded): out = theta*(1+c*s) + c*(kd@V); V computed from partials
// during staging — all regions uniform 2-3 loads/element. grid(145) x 256.
__global__ __launch_bounds__(256) void k_update(
    const float* __restrict__ W1, const float* __restrict__ b1,
    const float* __restrict__ W2, const float* __restrict__ b2,
    const float* __restrict__ gram, const float* __restrict__ dwp,
    const float* __restrict__ gbp, const float* __restrict__ gw2p,
    const float* __restrict__ Pb2, float* __restrict__ vout) {
  __shared__ float Vs[64][132];
  __shared__ float kds[4096];
  __shared__ float ss[64];
  __shared__ float sq[64];
  const int c0 = blockIdx.x * GCH;
  const int tid = threadIdx.x;

  // ---- V staging from partials ----
  if (c0 + GCH <= OFF_B1) {
    // W1 region: V = (s0+s1)*w2[k] - 2*W1
    for (int idx = tid; idx < 2048; idx += 256) {
      const int i = idx >> 5, dd = (idx & 31) * 4;
      const size_t o = (size_t)i * 16384 + c0 + dd;
      const f32x4 s0 = *(const f32x4*)&dwp[o];
      const f32x4 s1 = *(const f32x4*)&dwp[o + (size_t)NP * 16384];
      const f32x4 ww = *(const f32x4*)&W1[o];
      const float w2r = W2[i * HID + ((c0 + dd) >> 4)];
      #pragma unroll
      for (int c = 0; c < 4; ++c)
        Vs[i][dd + c] = (s0[c] + s1[c]) * w2r - 2.f * ww[c];
    }
  } else if (c0 + GCH <= OFF_W2) {
    // b1 region: V = gb1*w2 - 2*b1
    for (int idx = tid; idx < 2048; idx += 256) {
      const int i = idx >> 5, dd = (idx & 31) * 4;
      const size_t o = (size_t)i * HID + (c0 + dd - OFF_B1);
      const f32x4 g0 = *(const f32x4*)&gbp[o];
      const f32x4 g1 = *(const f32x4*)&gbp[o + (size_t)NP * HID];
      const f32x4 w2v = *(const f32x4*)&W2[o];
      const f32x4 b1v = *(const f32x4*)&b1[o];
      #pragma unroll
      for (int c = 0; c < 4; ++c)
        Vs[i][dd + c] = (g0[c] + g1[c]) * w2v[c] - 2.f * b1v[c];
    }
  } else if (c0 + GCH <= OFF_B2) {
    // W2 region: V = (d0+d1) + b1*gb1 - 2*w2  (dot precomputed in k_bwd)
    for (int idx = tid; idx < 2048; idx += 256) {
      const int i = idx >> 5, dd = (idx & 31) * 4;
      const size_t o = (size_t)i * HID + (c0 + dd - OFF_W2);
      const f32x4 d0 = *(const f32x4*)&gw2p[o];
      const f32x4 d1 = *(const f32x4*)&gw2p[o + (size_t)NP * HID];
      const f32x4 g0 = *(const f32x4*)&gbp[o];
      const f32x4 g1 = *(const f32x4*)&gbp[o + (size_t)NP * HID];
      const f32x4 b1v = *(const f32x4*)&b1[o];
      const f32x4 w2v = *(const f32x4*)&W2[o];
      #pragma unroll
      for (int c = 0; c < 4; ++c)
        Vs[i][dd + c] = (d0[c] + d1[c]) + b1v[c] * (g0[c] + g1[c]) - 2.f * w2v[c];
    }
  } else {
    // b2 block (c0 == 18432): only column 0 valid
    for (int idx = tid; idx < 2048; idx += 256) {
      const int i = idx >> 5, dd = (idx & 31) * 4;
      f32x4 v = {0.f, 0.f, 0.f, 0.f};
      if (dd == 0) {
        float sb = 0.f;
        #pragma unroll
        for (int q = 0; q < 8; ++q) sb += Pb2[i * 8 + q];
        v[0] = sb - 2.f * b2[i];
      }
      *(f32x4*)&Vs[i][dd] = v;
    }
  }

  if (tid < 64) sq[tid] = gram[tid * 65];
  __syncthreads();
  for (int q = tid; q < 4096; q += 256) {
    const int i = q >> 6, j = q & 63;
    const float d2 = fmaxf(sq[i] + sq[j] - 2.f * gram[q], 0.f);
    kds[q] = expf(-0.5f * d2);
  }
  __syncthreads();
  if (tid < 64) {
    float a = 0.f;
    for (int j = 0; j < 64; ++j) a += kds[tid * 64 + j];
    ss[tid] = a;
  }
  __syncthreads();
  const int col4 = (tid & 31) * 4;
  const int i0 = (tid >> 5) * 8;
  f32x4 acc[8] = {};
  for (int j = 0; j < 64; ++j) {
    const f32x4 vv = *(const f32x4*)&Vs[j][col4];
    const f32x4 k0 = *(const f32x4*)&kds[j * 64 + i0];
    const f32x4 k1 = *(const f32x4*)&kds[j * 64 + i0 + 4];
    #pragma unroll
    for (int a = 0; a < 4; ++a) {
      acc[a][0] = fmaf(k0[a], vv[0], acc[a][0]);
      acc[a][1] = fmaf(k0[a], vv[1], acc[a][1]);
      acc[a][2] = fmaf(k0[a], vv[2], acc[a][2]);
      acc[a][3] = fmaf(k0[a], vv[3], acc[a][3]);
    }
    #pragma unroll
    for (int a = 0; a < 4; ++a) {
      acc[a + 4][0] = fmaf(k1[a], vv[0], acc[a + 4][0]);
      acc[a + 4][1] = fmaf(k1[a], vv[1], acc[a + 4][1]);
      acc[a + 4][2] = fmaf(k1[a], vv[2], acc[a + 4][2]);
      acc[a + 4][3] = fmaf(k1[a], vv[3], acc[a + 4][3]);
    }
  }
  #pragma unroll
  for (int a = 0; a < 8; ++a) {
    const int i = i0 + a;
    const float f = 1.f + STEPC * ss[i];
    #pragma unroll
    for (int cc = 0; cc < 4; ++cc) {
      const int d = c0 + col4 + cc;
      if (d < DTOT) {
        const float th = theta_at(i, d, W1, b1, W2, b2);
        vout[(size_t)i * DTOT + d] = th * f + STEPC * acc[a][cc];
      }
    }
  }
}

extern "C" void kernel_launch(void* const* d_in, const int* in_sizes, int n_in,
                              void* d_out, int out_size, void* d_ws, size_t ws_size,
                              hipStream_t stream) {
  const float* W1 = (const float*)d_in[0];
  const float* b1 = (const float*)d_in[1];
  const float* W2 = (const float*)d_in[2];
  const float* b2 = (const float*)d_in[3];
  const float* X  = (const float*)d_in[4];
  const float* y  = (const float*)d_in[5];
  float* vout = (float*)d_out;

  float* Pb2   = (float*)d_ws;              // 512 f
  float* gpart = Pb2 + 512;                 // 593920 f
  float* gram  = gpart + NGBLK * 4096;      // 4096 f
  float* dwp   = gram + 4096;               // 2*64*1024*16 = 2097152 f
  float* gbp   = dwp + 2 * NP * HID * 16;   // 131072 f
  float* gw2p  = gbp + 2 * NP * HID;        // 131072 f
  short* W1b   = (short*)(gw2p + 2 * NP * HID);  // 1048576 s
  short* Xb    = W1b + NP * HID * DIN;      // 32768 s
  short* XtS   = Xb + BATCH * DIN;          // 32768 s
  short* ebf   = XtS + BATCH * DIN;         // 131072 s

  k_prep<<<512, 256, 0, stream>>>(W1, X, W1b, Xb, XtS);
  k_fwd_gram<<<512 + NGBLK, 512, 0, stream>>>(W1b, b1, W2, b2, Xb, y, ebf, Pb2, W1, gpart);
  k_bwd_red<<<1024 + 64, 512, 0, stream>>>(b1, W1, W1b, Xb, XtS, ebf, dwp, gbp, gw2p, gpart, gram);
  k_update<<<NGBLK, 256, 0, stream>>>(W1, b1, W2, b2, gram, dwp, gbp, gw2p, Pb2, vout);
}